// Round 2
// baseline (228.839 us; speedup 1.0000x reference)
//
#include <hip/hip_runtime.h>

// Problem constants (fixed by the reference setup_inputs()).
#define BB 8
#define CC 256
#define EE 18000
#define TT 4500
#define BT (BB * TT)   // 36000
#define BE (BB * EE)   // 144000

// ---------------- setup: CSR build (counts -> scan -> scatter) -------------

__global__ void zero_counts_kernel(int* __restrict__ counts) {
    int i = blockIdx.x * blockDim.x + threadIdx.x;
    if (i < BT) counts[i] = 0;
}

__global__ void count_kernel(const int* __restrict__ gid, int* __restrict__ counts) {
    int i = blockIdx.x * blockDim.x + threadIdx.x;
    if (i < BE) {
        int b = i / EE;
        int g = gid[i];
        atomicAdd(&counts[b * TT + g], 1);
    }
}

// exclusive prefix sum of counts[BT] into cursor[BT]; single block of 1024.
__global__ __launch_bounds__(1024) void scan_kernel(const int* __restrict__ counts,
                                                    int* __restrict__ cursor) {
    __shared__ int part[1024];
    const int t = threadIdx.x;
    const int CHUNK = 36;                 // 1024*36 = 36864 >= 36000
    int lo = t * CHUNK;
    int hi = lo + CHUNK; if (hi > BT) hi = BT;
    int s = 0;
    for (int i = lo; i < hi; ++i) s += counts[i];
    part[t] = s;
    __syncthreads();
    // Hillis-Steele inclusive scan over 1024 partials
    for (int d = 1; d < 1024; d <<= 1) {
        int v = (t >= d) ? part[t - d] : 0;
        __syncthreads();
        part[t] += v;
        __syncthreads();
    }
    int run = part[t] - s;                // exclusive prefix for this chunk
    for (int i = lo; i < hi; ++i) { cursor[i] = run; run += counts[i]; }
}

// scatter edges into perm[]; cursor becomes the END offset of each group.
__global__ void scatter_kernel(const int* __restrict__ gid,
                               int* __restrict__ cursor,
                               int* __restrict__ perm) {
    int i = blockIdx.x * blockDim.x + threadIdx.x;
    if (i < BE) {
        int b = i / EE;
        int g = gid[i];
        int p = atomicAdd(&cursor[b * TT + g], 1);
        perm[p] = i - b * EE;             // edge index local to batch
    }
}

// ---------------- main: gather-based segment mean --------------------------
// One block per (b, c). Stage the 72 KB row in LDS (coalesced float4), then
// each thread segment-sums 4 groups at a time (ILP-4 independent chains) via
// ds_read gathers — no atomics. Lanes take consecutive groups so perm reads
// stay within ~1 KB per wave (L2-resident, shared by all 256 channel blocks).

__global__ __launch_bounds__(256) void pool_kernel(const float* __restrict__ fe,
                                                   const int* __restrict__ counts,
                                                   const int* __restrict__ endo,
                                                   const int* __restrict__ perm,
                                                   float* __restrict__ out) {
    __shared__ float row[EE];             // 72000 B -> 2 blocks/CU
    const int b   = blockIdx.x / CC;
    const int c   = blockIdx.x % CC;
    const int tid = threadIdx.x;

    const float4* fe4  = reinterpret_cast<const float4*>(fe + (size_t)(b * CC + c) * EE);
    float4*       row4 = reinterpret_cast<float4*>(row);
    for (int i = tid; i < EE / 4; i += 256) row4[i] = fe4[i];
    __syncthreads();

    const int base = b * TT;
    float*    outb = out + (size_t)(b * CC + c) * TT;

    // 4500 groups / 256 threads = 17.58 -> 18 group-slots -> 5 chunks of 4
    for (int it = 0; it < 5; ++it) {
        int   g[4], n[4], e0[4];
        float acc[4] = {0.f, 0.f, 0.f, 0.f};
        int   kmax = 0;
#pragma unroll
        for (int j = 0; j < 4; ++j) {
            int gg = tid + (it * 4 + j) * 256;
            g[j] = gg;
            bool ok = gg < TT;
            int e1 = ok ? endo[base + gg]   : 0;
            int nn = ok ? counts[base + gg] : 0;
            n[j]  = nn;
            e0[j] = e1 - nn;
            kmax  = max(kmax, nn);
        }
        for (int k = 0; k < kmax; ++k) {
#pragma unroll
            for (int j = 0; j < 4; ++j) {
                if (k < n[j]) acc[j] += row[perm[e0[j] + k]];
            }
        }
#pragma unroll
        for (int j = 0; j < 4; ++j) {
            if (g[j] < TT)
                outb[g[j]] = acc[j] * (n[j] > 0 ? 1.0f / (float)n[j] : 0.0f);
        }
    }
}

extern "C" void kernel_launch(void* const* d_in, const int* in_sizes, int n_in,
                              void* d_out, int out_size, void* d_ws, size_t ws_size,
                              hipStream_t stream) {
    const float* fe  = (const float*)d_in[0];
    const int*   gid = (const int*)d_in[1];
    float*       out = (float*)d_out;

    // workspace ints: counts[BT] | cursor[BT] | perm[BE]  (864 KB total)
    int* counts = (int*)d_ws;
    int* cursor = counts + BT;
    int* perm   = cursor + BT;

    zero_counts_kernel<<<(BT + 255) / 256, 256, 0, stream>>>(counts);
    count_kernel<<<(BE + 255) / 256, 256, 0, stream>>>(gid, counts);
    scan_kernel<<<1, 1024, 0, stream>>>(counts, cursor);
    scatter_kernel<<<(BE + 255) / 256, 256, 0, stream>>>(gid, cursor, perm);
    pool_kernel<<<BB * CC, 256, 0, stream>>>(fe, counts, cursor, perm, out);
}

// Round 3
// 109.460 us; speedup vs baseline: 2.0906x; 2.0906x over previous
//
#include <hip/hip_runtime.h>
#include <hip/hip_fp16.h>

// Problem constants (fixed by reference setup_inputs()).
#define BB 8
#define CC 256
#define EE 18000
#define TT 4500
#define BT (BB * TT)     // 36000
#define BE (BB * EE)     // 144000
#define OFFW 4502        // u16 offsets per batch: TT entries + sentinel + pad (u32-even)

// ---------------- setup: counts -> per-batch scan -> rank scatter ----------

__global__ void zero_counts_kernel(int* __restrict__ counts) {
    int i = blockIdx.x * blockDim.x + threadIdx.x;
    if (i < BT) counts[i] = 0;
}

__global__ void count_kernel(const int* __restrict__ gid, int* __restrict__ counts) {
    int i = blockIdx.x * blockDim.x + threadIdx.x;
    if (i < BE) {
        int b = i / EE;
        atomicAdd(&counts[b * TT + gid[i]], 1);
    }
}

// one block per batch: exclusive scan of counts[b,0:TT] -> cursor (int, flat
// position base b*EE) and off16 (u16 per-batch CSR offsets with sentinel).
__global__ __launch_bounds__(1024) void scan_kernel(const int* __restrict__ counts,
                                                    int* __restrict__ cursor,
                                                    unsigned short* __restrict__ off16) {
    __shared__ int part[1024];
    const int b = blockIdx.x;
    const int t = threadIdx.x;
    const int CHUNK = 5;                         // 1024*5 >= 4500
    int lo = t * CHUNK;
    int hi = lo + CHUNK; if (hi > TT) hi = TT;
    if (lo > TT) lo = TT;
    int s = 0;
    for (int i = lo; i < hi; ++i) s += counts[b * TT + i];
    part[t] = s;
    __syncthreads();
    for (int d = 1; d < 1024; d <<= 1) {
        int v = (t >= d) ? part[t - d] : 0;
        __syncthreads();
        part[t] += v;
        __syncthreads();
    }
    int run = part[t] - s;                       // per-batch exclusive prefix
    for (int i = lo; i < hi; ++i) {
        cursor[b * TT + i] = b * EE + run;
        off16[b * OFFW + i] = (unsigned short)run;
        run += counts[b * TT + i];
    }
    if (t == 0) {
        off16[b * OFFW + TT]     = (unsigned short)EE;  // sentinel
        off16[b * OFFW + TT + 1] = (unsigned short)EE;  // pad (u32-even)
    }
}

// rank16[b*EE + e] = CSR position of edge e within batch b (u16)
__global__ void scatter_kernel(const int* __restrict__ gid,
                               int* __restrict__ cursor,
                               unsigned short* __restrict__ rank16) {
    int i = blockIdx.x * blockDim.x + threadIdx.x;
    if (i < BE) {
        int b = i / EE;
        int p = atomicAdd(&cursor[b * TT + gid[i]], 1);
        rank16[i] = (unsigned short)(p - b * EE);
    }
}

// ---------------- main: scatter-on-read + contiguous sweep -----------------
// One block per (b,c). Coalesced fe float4 + rank ushort4 reads; values land
// in LDS in CSR order (fp16, 36KB). Offsets staged in LDS (9KB). Each thread
// sweeps a contiguous ~70-position window, fully summing every group whose
// START lies in its window (tail extension; no atomics; empties write 0).
// 45KB LDS -> 3 blocks/CU, 12 waves.

__global__ __launch_bounds__(256) void pool_kernel(const float* __restrict__ fe,
                                                   const unsigned short* __restrict__ rank16,
                                                   const unsigned short* __restrict__ off16,
                                                   float* __restrict__ out) {
    __shared__ __half vals[EE];                  // 36000 B, CSR-ordered values
    __shared__ unsigned short offs[OFFW];        // 9004 B
    const int b   = blockIdx.x >> 8;             // CC == 256
    const int c   = blockIdx.x & 255;
    const int tid = threadIdx.x;

    // stage offsets coalesced as u32
    {
        const unsigned int* src = (const unsigned int*)(off16 + b * OFFW);
        unsigned int*       dst = (unsigned int*)offs;
        for (int i = tid; i < OFFW / 2; i += 256) dst[i] = src[i];
    }

    // scatter row into vals (CSR order)
    const float4*  fe4 = (const float4*)(fe + (size_t)(b * CC + c) * EE);
    const ushort4* rk4 = (const ushort4*)(rank16 + (size_t)b * EE);
#pragma unroll
    for (int i = 0; i < 18; ++i) {
        int idx = tid + (i << 8);
        if (idx < EE / 4) {
            float4  v = fe4[idx];
            ushort4 r = rk4[idx];
            vals[r.x] = __float2half(v.x);
            vals[r.y] = __float2half(v.y);
            vals[r.z] = __float2half(v.z);
            vals[r.w] = __float2half(v.w);
        }
    }
    __syncthreads();

    // contiguous sweep: thread owns CSR window [lo, hi)
    int lo = (tid * EE) >> 8;
    int hi = ((tid + 1) * EE) >> 8;
    if (tid == 255) hi = EE + 1;                 // catch trailing empty groups

    // lower_bound: first g with offs[g] >= lo
    int a = 0, bd = TT;
    while (a < bd) {
        int m = (a + bd) >> 1;
        if ((int)offs[m] < lo) a = m + 1; else bd = m;
    }

    float* outb = out + (size_t)(b * CC + c) * TT;
    for (int g = a; g < TT; ++g) {
        int s0 = offs[g];
        if (s0 >= hi) break;                     // group starts beyond window
        int e0 = offs[g + 1];
        float sum = 0.f;
        for (int p = s0; p < e0; ++p) sum += __half2float(vals[p]);
        outb[g] = (e0 > s0) ? sum / (float)(e0 - s0) : 0.0f;
    }
}

extern "C" void kernel_launch(void* const* d_in, const int* in_sizes, int n_in,
                              void* d_out, int out_size, void* d_ws, size_t ws_size,
                              hipStream_t stream) {
    const float* fe  = (const float*)d_in[0];
    const int*   gid = (const int*)d_in[1];
    float*       out = (float*)d_out;

    // ws layout (bytes): counts[BT] int | cursor[BT] int | off16[BB*OFFW] u16 | rank16[BE] u16
    int*            counts = (int*)d_ws;
    int*            cursor = counts + BT;
    unsigned short* off16  = (unsigned short*)(cursor + BT);
    unsigned short* rank16 = off16 + BB * OFFW;

    zero_counts_kernel<<<(BT + 255) / 256, 256, 0, stream>>>(counts);
    count_kernel<<<(BE + 255) / 256, 256, 0, stream>>>(gid, counts);
    scan_kernel<<<BB, 1024, 0, stream>>>(counts, cursor, off16);
    scatter_kernel<<<(BE + 255) / 256, 256, 0, stream>>>(gid, cursor, rank16);
    pool_kernel<<<BB * CC, 256, 0, stream>>>(fe, rank16, off16, out);
}

// Round 4
// 95.112 us; speedup vs baseline: 2.4060x; 1.1508x over previous
//
#include <hip/hip_runtime.h>
#include <hip/hip_fp16.h>

// Problem constants (fixed by reference setup_inputs()).
#define BB 8
#define CC 256
#define EE 18000
#define TT 4500
#define BT (BB * TT)     // 36000
#define BE (BB * EE)     // 144000
#define OFFW 4502        // u16 offsets per batch: TT entries + sentinel + pad

// ---------------- setup: counts -> per-batch scan -> rank scatter ----------

__global__ void zero_counts_kernel(int* __restrict__ counts) {
    int i = blockIdx.x * blockDim.x + threadIdx.x;
    if (i < BT) counts[i] = 0;
}

__global__ void count_kernel(const int* __restrict__ gid, int* __restrict__ counts) {
    int i = blockIdx.x * blockDim.x + threadIdx.x;
    if (i < BE) {
        int b = i / EE;
        atomicAdd(&counts[b * TT + gid[i]], 1);
    }
}

// one block per batch: exclusive scan of counts[b,0:TT] -> cursor (int, flat
// position base b*EE) and off16 (u16 per-batch CSR offsets with sentinel).
__global__ __launch_bounds__(1024) void scan_kernel(const int* __restrict__ counts,
                                                    int* __restrict__ cursor,
                                                    unsigned short* __restrict__ off16) {
    __shared__ int part[1024];
    const int b = blockIdx.x;
    const int t = threadIdx.x;
    const int CHUNK = 5;                         // 1024*5 >= 4500
    int lo = t * CHUNK;
    int hi = lo + CHUNK; if (hi > TT) hi = TT;
    if (lo > TT) lo = TT;
    int s = 0;
    for (int i = lo; i < hi; ++i) s += counts[b * TT + i];
    part[t] = s;
    __syncthreads();
    for (int d = 1; d < 1024; d <<= 1) {
        int v = (t >= d) ? part[t - d] : 0;
        __syncthreads();
        part[t] += v;
        __syncthreads();
    }
    int run = part[t] - s;                       // per-batch exclusive prefix
    for (int i = lo; i < hi; ++i) {
        cursor[b * TT + i] = b * EE + run;
        off16[b * OFFW + i] = (unsigned short)run;
        run += counts[b * TT + i];
    }
    if (t == 0) {
        off16[b * OFFW + TT]     = (unsigned short)EE;  // sentinel
        off16[b * OFFW + TT + 1] = (unsigned short)EE;  // pad
    }
}

// rank16[b*EE + e] = CSR position of edge e within batch b (u16)
__global__ void scatter_kernel(const int* __restrict__ gid,
                               int* __restrict__ cursor,
                               unsigned short* __restrict__ rank16) {
    int i = blockIdx.x * blockDim.x + threadIdx.x;
    if (i < BE) {
        int b = i / EE;
        int p = atomicAdd(&cursor[b * TT + gid[i]], 1);
        rank16[i] = (unsigned short)(p - b * EE);
    }
}

// g0tab[b*512 + t] = first group whose CSR start >= window start of thread t.
// Depends only on (b, t) — computed once, shared by all 256 channel blocks.
__global__ __launch_bounds__(512) void g0_kernel(const unsigned short* __restrict__ off16,
                                                 unsigned short* __restrict__ g0tab) {
    const int b = blockIdx.x;
    const int t = threadIdx.x;
    const int lo = (t * EE) >> 9;
    const unsigned short* offs = off16 + b * OFFW;
    int a = 0, bd = TT;
    while (a < bd) {
        int m = (a + bd) >> 1;
        if ((int)offs[m] < lo) a = m + 1; else bd = m;
    }
    g0tab[(b << 9) + t] = (unsigned short)a;
}

// ---------------- main: scatter-on-read + contiguous sweep -----------------
// One block per (b,c), 512 threads. Coalesced fe float4 + rank ushort4 reads;
// values land in LDS in CSR order (fp16, 36KB -> 4 blocks/CU, 32 waves = 100%
// occupancy). Offsets read from global (L1-resident, shared by 256 blocks).
// Each thread sweeps a contiguous ~35-position window; one offset load per
// group (s0 chains from previous e0); empties write 0.

__global__ __launch_bounds__(512, 8) void pool_kernel(const float* __restrict__ fe,
                                                      const unsigned short* __restrict__ rank16,
                                                      const unsigned short* __restrict__ off16,
                                                      const unsigned short* __restrict__ g0tab,
                                                      float* __restrict__ out) {
    __shared__ __half vals[EE];                  // 36000 B
    const int b   = blockIdx.x >> 8;             // CC == 256
    const int c   = blockIdx.x & 255;
    const int tid = threadIdx.x;

    // scatter row into vals (CSR order)
    const float4*  fe4 = (const float4*)(fe + (size_t)(b * CC + c) * EE);
    const ushort4* rk4 = (const ushort4*)(rank16 + (size_t)b * EE);
#pragma unroll
    for (int i = 0; i < 9; ++i) {                // 9*512 = 4608 >= 4500
        int idx = tid + (i << 9);
        if (idx < EE / 4) {
            float4  v = fe4[idx];
            ushort4 r = rk4[idx];
            vals[r.x] = __float2half(v.x);
            vals[r.y] = __float2half(v.y);
            vals[r.z] = __float2half(v.z);
            vals[r.w] = __float2half(v.w);
        }
    }
    __syncthreads();

    // contiguous sweep: thread owns CSR window [lo, hi)
    const int hi = (tid == 511) ? (EE + 1) : (((tid + 1) * EE) >> 9);

    const unsigned short* offs = off16 + b * OFFW;
    int    g    = g0tab[(b << 9) + tid];
    int    s0   = offs[g];
    float* outb = out + (size_t)(b * CC + c) * TT;

    while (g < TT && s0 < hi) {
        int   e0  = offs[g + 1];
        float sum = 0.f;
        for (int p = s0; p < e0; ++p) sum += __half2float(vals[p]);
        outb[g] = (e0 > s0) ? sum / (float)(e0 - s0) : 0.0f;
        ++g;
        s0 = e0;                                 // next group's start == this end
    }
}

extern "C" void kernel_launch(void* const* d_in, const int* in_sizes, int n_in,
                              void* d_out, int out_size, void* d_ws, size_t ws_size,
                              hipStream_t stream) {
    const float* fe  = (const float*)d_in[0];
    const int*   gid = (const int*)d_in[1];
    float*       out = (float*)d_out;

    // ws: counts[BT] int | cursor[BT] int | off16[BB*OFFW] u16 | rank16[BE] u16 | g0tab[BB*512] u16
    int*            counts = (int*)d_ws;
    int*            cursor = counts + BT;
    unsigned short* off16  = (unsigned short*)(cursor + BT);
    unsigned short* rank16 = off16 + BB * OFFW;
    unsigned short* g0tab  = rank16 + BE;

    zero_counts_kernel<<<(BT + 255) / 256, 256, 0, stream>>>(counts);
    count_kernel<<<(BE + 255) / 256, 256, 0, stream>>>(gid, counts);
    scan_kernel<<<BB, 1024, 0, stream>>>(counts, cursor, off16);
    scatter_kernel<<<(BE + 255) / 256, 256, 0, stream>>>(gid, cursor, rank16);
    g0_kernel<<<BB, 512, 0, stream>>>(off16, g0tab);
    pool_kernel<<<BB * CC, 512, 0, stream>>>(fe, rank16, off16, g0tab, out);
}

// Round 5
// 67.018 us; speedup vs baseline: 3.4146x; 1.4192x over previous
//
#include <hip/hip_runtime.h>

// Problem constants (fixed by reference setup_inputs()).
#define BB 8
#define CC 256
#define EE 18000
#define TT 4500
#define BT (BB * TT)     // 36000
#define BE (BB * EE)     // 144000
#define W  36            // real elements per scan window
#define S  37            // padded stride (37 words: conflict-free, 2 lanes/bank)
#define NW 500           // 500 * 36 = 18000 exactly
#define PADDED (NW * S)  // 18500 floats = 74000 B

// ---------------- setup: counts -> per-batch scan -> rank scatter ----------

__global__ void zero_counts_kernel(int* __restrict__ counts) {
    int i = blockIdx.x * blockDim.x + threadIdx.x;
    if (i < BT) counts[i] = 0;
}

__global__ void count_kernel(const int* __restrict__ gid, int* __restrict__ counts) {
    int i = blockIdx.x * blockDim.x + threadIdx.x;
    if (i < BE) {
        int b = i / EE;
        atomicAdd(&counts[b * TT + gid[i]], 1);
    }
}

// one block per batch: exclusive scan of counts[b,:] -> cursor (scatter base),
// pend16[g] = padded index of group's LAST csr element (0 if end==0),
// inv32[g] = 1/count (0 for empty).
__global__ __launch_bounds__(1024) void scan_kernel(const int* __restrict__ counts,
                                                    int* __restrict__ cursor,
                                                    unsigned short* __restrict__ pend16,
                                                    float* __restrict__ inv32) {
    __shared__ int part[1024];
    const int b = blockIdx.x;
    const int t = threadIdx.x;
    const int CHUNK = 5;                          // 1024*5 >= 4500
    int lo = t * CHUNK; if (lo > TT) lo = TT;
    int hi = lo + CHUNK; if (hi > TT) hi = TT;
    int s = 0;
    for (int i = lo; i < hi; ++i) s += counts[b * TT + i];
    part[t] = s;
    __syncthreads();
    for (int d = 1; d < 1024; d <<= 1) {
        int v = (t >= d) ? part[t - d] : 0;
        __syncthreads();
        part[t] += v;
        __syncthreads();
    }
    int run = part[t] - s;                        // per-batch exclusive prefix
    for (int i = lo; i < hi; ++i) {
        int cnt = counts[b * TT + i];
        cursor[b * TT + i] = b * EE + run;
        int end = run + cnt;
        pend16[b * TT + i] = (end > 0) ? (unsigned short)((end - 1) + (end - 1) / W) : 0;
        inv32[b * TT + i]  = (cnt > 0) ? 1.0f / (float)cnt : 0.0f;
        run = end;
    }
}

// prank16[b*EE + e] = PADDED CSR position of edge e within batch b
__global__ void scatter_kernel(const int* __restrict__ gid,
                               int* __restrict__ cursor,
                               unsigned short* __restrict__ prank16) {
    int i = blockIdx.x * blockDim.x + threadIdx.x;
    if (i < BE) {
        int b = i / EE;
        int p = atomicAdd(&cursor[b * TT + gid[i]], 1) - b * EE;  // real rank
        prank16[i] = (unsigned short)(p + p / W);                 // padded rank
    }
}

// ---------------- main: scatter + block prefix-scan + regular epilogue -----
// One block per (b,c), 512 threads, 76KB LDS -> 2 blocks/CU.
// 1) coalesced fe float4 + prank ushort4; scatter fp32 into padded CSR order
// 2) 3-phase prefix scan (windows kept in registers between phases)
// 3) out[g] = (P[pend[g]] - P[pend[g-1]]) * inv[g]; lanes write consecutive
//    groups -> perfectly coalesced stores (fixes 3.7x write amplification).

__global__ __launch_bounds__(512, 2) void pool_kernel(const float* __restrict__ fe,
                                                      const unsigned short* __restrict__ prank16,
                                                      const unsigned short* __restrict__ pend16,
                                                      const float* __restrict__ inv32,
                                                      float* __restrict__ out) {
    __shared__ float vals[PADDED];               // 74000 B
    __shared__ float part[512];                  //  2048 B
    const int b   = blockIdx.x >> 8;             // CC == 256
    const int c   = blockIdx.x & 255;
    const int tid = threadIdx.x;

    // zero each window's pad slot (never written by scatter, never read as P)
    if (tid < NW) vals[S * tid + W] = 0.0f;

    // scatter row into vals (padded CSR order)
    const float4*  fe4 = (const float4*)(fe + (size_t)(b * CC + c) * EE);
    const ushort4* rk4 = (const ushort4*)(prank16 + (size_t)b * EE);
#pragma unroll
    for (int i = 0; i < 9; ++i) {                // 9*512 = 4608 >= 4500
        int idx = tid + (i << 9);
        if (idx < EE / 4) {
            float4  v = fe4[idx];
            ushort4 r = rk4[idx];
            vals[r.x] = v.x;
            vals[r.y] = v.y;
            vals[r.z] = v.z;
            vals[r.w] = v.w;
        }
    }
    __syncthreads();

    // phase A: per-thread serial sum of its 36-word window (kept in regs)
    float v[W];
    float sum = 0.0f;
    const int base = S * tid;
    if (tid < NW) {
#pragma unroll
        for (int k = 0; k < W; ++k) { v[k] = vals[base + k]; sum += v[k]; }
    }
    part[tid] = sum;
    __syncthreads();

    // phase B: wave 0 scans the 512 partials (8 per lane + shfl scan)
    if (tid < 64) {
        float ps[8];
        float run = 0.0f;
#pragma unroll
        for (int j = 0; j < 8; ++j) { run += part[tid * 8 + j]; ps[j] = run; }
        float tot = run, sc = run;
#pragma unroll
        for (int d = 1; d < 64; d <<= 1) {
            float o = __shfl_up(sc, d, 64);
            if (tid >= d) sc += o;
        }
        float excl = sc - tot;
#pragma unroll
        for (int j = 0; j < 8; ++j) part[tid * 8 + j] = ps[j] + excl;
    }
    __syncthreads();

    // phase C: write back inclusive running prefix
    if (tid < NW) {
        float run = (tid > 0) ? part[tid - 1] : 0.0f;
#pragma unroll
        for (int k = 0; k < W; ++k) { run += v[k]; vals[base + k] = run; }
    }
    __syncthreads();

    // epilogue: regular, coalesced
    const unsigned short* pe = pend16 + b * TT;
    const float*          iv = inv32 + b * TT;
    float*                outb = out + (size_t)(b * CC + c) * TT;
#pragma unroll
    for (int k = 0; k < 9; ++k) {                // 9*512 = 4608 >= 4500
        int g = tid + (k << 9);
        if (g < TT) {
            float Pa = vals[pe[g]];
            float Pb = (g > 0) ? vals[pe[g - 1]] : 0.0f;
            outb[g] = (Pa - Pb) * iv[g];
        }
    }
}

extern "C" void kernel_launch(void* const* d_in, const int* in_sizes, int n_in,
                              void* d_out, int out_size, void* d_ws, size_t ws_size,
                              hipStream_t stream) {
    const float* fe  = (const float*)d_in[0];
    const int*   gid = (const int*)d_in[1];
    float*       out = (float*)d_out;

    // ws: counts[BT] int | cursor[BT] int | inv32[BT] f32 | pend16[BT] u16 | prank16[BE] u16
    int*            counts  = (int*)d_ws;
    int*            cursor  = counts + BT;
    float*          inv32   = (float*)(cursor + BT);
    unsigned short* pend16  = (unsigned short*)(inv32 + BT);
    unsigned short* prank16 = pend16 + BT;

    zero_counts_kernel<<<(BT + 255) / 256, 256, 0, stream>>>(counts);
    count_kernel<<<(BE + 255) / 256, 256, 0, stream>>>(gid, counts);
    scan_kernel<<<BB, 1024, 0, stream>>>(counts, cursor, pend16, inv32);
    scatter_kernel<<<(BE + 255) / 256, 256, 0, stream>>>(gid, cursor, prank16);
    pool_kernel<<<BB * CC, 512, 0, stream>>>(fe, prank16, pend16, inv32, out);
}